// Round 1
// baseline (1387.459 us; speedup 1.0000x reference)
//
#include <hip/hip_runtime.h>
#include <math.h>

#define N_NODES 50000
#define N_EDGES 800000
#define N_GRAPHS 64
#define F_INN 128
#define F_HID 192
#define F_OUTT 128
#define N_CLS 10

// ---------------- CSR build ----------------
__global__ void k_deg(const int* __restrict__ row, int* __restrict__ cnt) {
    int e = blockIdx.x * 256 + threadIdx.x;
    if (e < N_EDGES) atomicAdd(&cnt[row[e]], 1);
}

__global__ void k_dis(const int* __restrict__ cnt, float* __restrict__ dis) {
    int i = blockIdx.x * 256 + threadIdx.x;
    if (i < N_NODES) {
        int d = cnt[i];
        dis[i] = d > 0 ? rsqrtf((float)d) : 0.f;
    }
}

// 3-phase exclusive scan over cnt[N] -> rp[N+1]
__global__ void k_scan1(const int* __restrict__ cnt, int* __restrict__ rp,
                        int* __restrict__ part) {
    __shared__ int s[256];
    int base = blockIdx.x * 512;
    int i0 = base + 2 * threadIdx.x;
    int v0 = (i0 < N_NODES) ? cnt[i0] : 0;
    int v1 = (i0 + 1 < N_NODES) ? cnt[i0 + 1] : 0;
    int tsum = v0 + v1;
    s[threadIdx.x] = tsum;
    __syncthreads();
    for (int off = 1; off < 256; off <<= 1) {
        int val = (threadIdx.x >= off) ? s[threadIdx.x - off] : 0;
        __syncthreads();
        s[threadIdx.x] += val;
        __syncthreads();
    }
    int excl = s[threadIdx.x] - tsum;
    if (i0 < N_NODES) rp[i0] = excl;
    if (i0 + 1 < N_NODES) rp[i0 + 1] = excl + v0;
    if (threadIdx.x == 255) part[blockIdx.x] = s[255];
}

__global__ void k_scan2(int* __restrict__ part, int nb) {
    __shared__ int s[128];
    int t = threadIdx.x;
    int v = (t < nb) ? part[t] : 0;
    s[t] = v;
    __syncthreads();
    for (int off = 1; off < 128; off <<= 1) {
        int val = (t >= off) ? s[t - off] : 0;
        __syncthreads();
        s[t] += val;
        __syncthreads();
    }
    if (t < nb) part[t] = s[t] - v;  // exclusive
}

__global__ void k_scan3(int* __restrict__ rp, const int* __restrict__ part) {
    int add = part[blockIdx.x];
    int i0 = blockIdx.x * 512 + 2 * threadIdx.x;
    if (i0 < N_NODES) rp[i0] += add;
    if (i0 + 1 < N_NODES) rp[i0 + 1] += add;
    if (blockIdx.x == 0 && threadIdx.x == 0) rp[N_NODES] = N_EDGES;
}

__global__ void k_scatter(const int* __restrict__ row, const int* __restrict__ col,
                          const float* __restrict__ dis, const int* __restrict__ rp,
                          int* __restrict__ fill, int* __restrict__ cols,
                          float* __restrict__ wv) {
    int e = blockIdx.x * 256 + threadIdx.x;
    if (e < N_EDGES) {
        int r = row[e], c = col[e];
        int pos = rp[r] + atomicAdd(&fill[r], 1);
        cols[pos] = c;
        wv[pos] = -dis[r] * dis[c];
    }
}

// ---------------- SpMV: y = alpha * (L_hat @ h) + beta * z ----------------
// one wave per row; lane-per-feature (stride-64), coalesced row reads
template <int F>
__global__ void k_spmv(const int* __restrict__ rp, const int* __restrict__ cols,
                       const float* __restrict__ wv, const float* __restrict__ h,
                       const float* __restrict__ z, float alpha, float beta,
                       float* __restrict__ y) {
    int wave = threadIdx.x >> 6;
    int lane = threadIdx.x & 63;
    int r = blockIdx.x * 4 + wave;
    if (r >= N_NODES) return;
    int e0 = rp[r], e1 = rp[r + 1];
    constexpr int NF = F / 64;
    float acc[NF];
#pragma unroll
    for (int i = 0; i < NF; i++) acc[i] = 0.f;
    for (int e = e0; e < e1; e++) {
        int c = cols[e];
        float w = wv[e];
        const float* hp = h + (long)c * F + lane;
#pragma unroll
        for (int i = 0; i < NF; i++) acc[i] += w * hp[i * 64];
    }
    float* yp = y + (long)r * F + lane;
    if (beta != 0.f) {
        const float* zp = z + (long)r * F + lane;
#pragma unroll
        for (int i = 0; i < NF; i++) yp[i * 64] = alpha * acc[i] + beta * zp[i * 64];
    } else {
#pragma unroll
        for (int i = 0; i < NF; i++) yp[i * 64] = alpha * acc[i];
    }
}

// ---------------- fused 3-matrix GEMM: C = A0@W[0]+A1@W[1]+A2@W[2]+bias -------
// 64x64 tile, 256 threads, 4x4 micro-tile, K-chunk 16
__global__ __launch_bounds__(256) void k_gemm3(
    const float* __restrict__ A0, const float* __restrict__ A1,
    const float* __restrict__ A2, const float* __restrict__ W,
    const float* __restrict__ bias, float* __restrict__ C, int Fin, int Fout) {
    __shared__ float As[16][68];  // [k][m], stride 68 keeps float4 alignment
    __shared__ float Bs[16][64];  // [k][n]
    int tid = threadIdx.x;
    int tx = tid & 15, ty = tid >> 4;
    int mBase = blockIdx.x * 64;
    int nBase = blockIdx.y * 64;
    const float* Aarr[3] = {A0, A1, A2};
    float acc[4][4] = {};
    int nChunks = (3 * Fin) / 16;
    int lm = tid >> 4;  // A-load row group 0..15
    int lk = tid & 15;  // k within chunk
    int bk = tid >> 6;  // B-load k group 0..3
    int bn = tid & 63;  // n
    for (int ch = 0; ch < nChunks; ch++) {
        int kg = ch * 16;
        int j = kg / Fin;
        int kk = kg % Fin;
        const float* A = Aarr[j];
        const float* Wj = W + ((long)j * Fin + kk) * Fout + nBase;
#pragma unroll
        for (int i = 0; i < 4; i++) {
            int m = mBase + lm + i * 16;
            float v = (m < N_NODES) ? A[(long)m * Fin + kk + lk] : 0.f;
            As[lk][lm + i * 16] = v;
        }
#pragma unroll
        for (int i = 0; i < 4; i++) {
            int k = bk + i * 4;
            Bs[k][bn] = Wj[(long)k * Fout + bn];
        }
        __syncthreads();
#pragma unroll
        for (int k = 0; k < 16; k++) {
            float4 a4 = *(const float4*)&As[k][ty * 4];
            float4 b4 = *(const float4*)&Bs[k][tx * 4];
            float av[4] = {a4.x, a4.y, a4.z, a4.w};
            float bv[4] = {b4.x, b4.y, b4.z, b4.w};
#pragma unroll
            for (int i = 0; i < 4; i++)
#pragma unroll
                for (int jj = 0; jj < 4; jj++) acc[i][jj] += av[i] * bv[jj];
        }
        __syncthreads();
    }
#pragma unroll
    for (int i = 0; i < 4; i++) {
        int m = mBase + ty * 4 + i;
        if (m < N_NODES) {
#pragma unroll
            for (int jj = 0; jj < 4; jj++) {
                int n = nBase + tx * 4 + jj;
                C[(long)m * Fout + n] = acc[i][jj] + bias[n];
            }
        }
    }
}

// ---------------- pooling + head ----------------
__global__ void k_pool(const float* __restrict__ h, const int* __restrict__ batch,
                       float* __restrict__ pooled) {
    int g = blockIdx.x;
    int f = threadIdx.x;  // 128
    int a = 0, b = N_NODES;
    while (a < b) { int m = (a + b) >> 1; if (batch[m] < g) a = m + 1; else b = m; }
    int lo = a;
    a = lo; b = N_NODES;
    while (a < b) { int m = (a + b) >> 1; if (batch[m] < g + 1) a = m + 1; else b = m; }
    int hi = a;
    float acc = 0.f;
    for (int n = lo; n < hi; n++) acc += h[(long)n * F_OUTT + f];
    pooled[g * F_OUTT + f] = acc / fmaxf((float)(hi - lo), 1.f);
}

__global__ void k_head(const float* __restrict__ pooled, const float* __restrict__ fcw,
                       const float* __restrict__ fcb, float* __restrict__ out) {
    int g = blockIdx.x;
    int c = threadIdx.x;  // 64 threads, lanes >= N_CLS idle
    __shared__ float sl[N_CLS];
    float l = 0.f;
    if (c < N_CLS) {
        l = fcb[c];
        for (int k = 0; k < F_OUTT; k++) l += pooled[g * F_OUTT + k] * fcw[k * N_CLS + c];
        sl[c] = l;
    }
    __syncthreads();
    if (c < N_CLS) {
        float m = -1e30f;
        for (int i = 0; i < N_CLS; i++) m = fmaxf(m, sl[i]);
        float s = 0.f;
        for (int i = 0; i < N_CLS; i++) s += expf(sl[i] - m);
        out[g * N_CLS + c] = l - m - logf(s);
    }
}

extern "C" void kernel_launch(void* const* d_in, const int* in_sizes, int n_in,
                              void* d_out, int out_size, void* d_ws, size_t ws_size,
                              hipStream_t stream) {
    const float* x = (const float*)d_in[0];
    const int* ei = (const int*)d_in[1];
    const int* batch = (const int*)d_in[2];
    const float* W1 = (const float*)d_in[3];
    const float* b1 = (const float*)d_in[4];
    const float* W2 = (const float*)d_in[5];
    const float* b2 = (const float*)d_in[6];
    const float* W3 = (const float*)d_in[7];
    const float* b3 = (const float*)d_in[8];
    const float* fcw = (const float*)d_in[9];
    const float* fcb = (const float*)d_in[10];
    float* out = (float*)d_out;
    const int* row = ei;
    const int* col = ei + N_EDGES;

    char* p = (char*)d_ws;
    auto carve = [&](size_t bytes) {
        char* q = p;
        p += (bytes + 255) & ~(size_t)255;
        return q;
    };
    int* cnt = (int*)carve(N_NODES * 4);
    int* fill = (int*)carve(N_NODES * 4);
    float* dis = (float*)carve(N_NODES * 4);
    int* rp = (int*)carve((N_NODES + 1) * 4);
    int* part = (int*)carve(128 * 4);
    int* cols = (int*)carve((size_t)N_EDGES * 4);
    float* wv = (float*)carve((size_t)N_EDGES * 4);
    size_t hbytes = (size_t)N_NODES * 192 * 4;
    float* bufA = (float*)carve(hbytes);
    float* bufB = (float*)carve(hbytes);
    float* bufC = (float*)carve(hbytes);
    float* bufD = (float*)carve(hbytes);
    float* pooled = (float*)carve(N_GRAPHS * F_OUTT * 4);

    hipMemsetAsync(cnt, 0, N_NODES * 4, stream);
    hipMemsetAsync(fill, 0, N_NODES * 4, stream);

    k_deg<<<(N_EDGES + 255) / 256, 256, 0, stream>>>(row, cnt);
    k_dis<<<(N_NODES + 255) / 256, 256, 0, stream>>>(cnt, dis);
    int nb = (N_NODES + 511) / 512;  // 98
    k_scan1<<<nb, 256, 0, stream>>>(cnt, rp, part);
    k_scan2<<<1, 128, 0, stream>>>(part, nb);
    k_scan3<<<nb, 256, 0, stream>>>(rp, part);
    k_scatter<<<(N_EDGES + 255) / 256, 256, 0, stream>>>(row, col, dis, rp, fill, cols, wv);

    const int spmvGrid = (N_NODES + 3) / 4;  // 4 rows (waves) per block

    // Layer 1: in=x (128) -> out=bufA (192)
    k_spmv<128><<<spmvGrid, 256, 0, stream>>>(rp, cols, wv, x, x, 1.f, 0.f, bufB);
    k_spmv<128><<<spmvGrid, 256, 0, stream>>>(rp, cols, wv, bufB, x, 2.f, -1.f, bufC);
    {
        dim3 g((N_NODES + 63) / 64, 192 / 64);
        k_gemm3<<<g, 256, 0, stream>>>(x, bufB, bufC, W1, b1, bufA, 128, 192);
    }
    // Layer 2: in=bufA (192) -> out=bufD (192)
    k_spmv<192><<<spmvGrid, 256, 0, stream>>>(rp, cols, wv, bufA, bufA, 1.f, 0.f, bufB);
    k_spmv<192><<<spmvGrid, 256, 0, stream>>>(rp, cols, wv, bufB, bufA, 2.f, -1.f, bufC);
    {
        dim3 g((N_NODES + 63) / 64, 192 / 64);
        k_gemm3<<<g, 256, 0, stream>>>(bufA, bufB, bufC, W2, b2, bufD, 192, 192);
    }
    // Layer 3: in=bufD (192) -> out=bufA (128)
    k_spmv<192><<<spmvGrid, 256, 0, stream>>>(rp, cols, wv, bufD, bufD, 1.f, 0.f, bufB);
    k_spmv<192><<<spmvGrid, 256, 0, stream>>>(rp, cols, wv, bufB, bufD, 2.f, -1.f, bufC);
    {
        dim3 g((N_NODES + 63) / 64, 128 / 64);
        k_gemm3<<<g, 256, 0, stream>>>(bufD, bufB, bufC, W3, b3, bufA, 192, 128);
    }

    k_pool<<<N_GRAPHS, F_OUTT, 0, stream>>>(bufA, batch, pooled);
    k_head<<<N_GRAPHS, 64, 0, stream>>>(pooled, fcw, fcb, out);
}

// Round 2
// 1310.463 us; speedup vs baseline: 1.0588x; 1.0588x over previous
//
#include <hip/hip_runtime.h>
#include <math.h>

#define N_NODES 50000
#define N_EDGES 800000
#define N_GRAPHS 64
#define F_INN 128
#define F_HID 192
#define F_OUTT 128
#define N_CLS 10
#define POOL_CHUNK 128

// ---------------- CSR build ----------------
__global__ void k_deg(const int* __restrict__ row, int* __restrict__ cnt) {
    int e = blockIdx.x * 256 + threadIdx.x;
    if (e < N_EDGES) atomicAdd(&cnt[row[e]], 1);
}

__global__ void k_dis(const int* __restrict__ cnt, float* __restrict__ dis) {
    int i = blockIdx.x * 256 + threadIdx.x;
    if (i < N_NODES) {
        int d = cnt[i];
        dis[i] = d > 0 ? rsqrtf((float)d) : 0.f;
    }
}

// 3-phase exclusive scan over cnt[N] -> rp[N+1]
__global__ void k_scan1(const int* __restrict__ cnt, int* __restrict__ rp,
                        int* __restrict__ part) {
    __shared__ int s[256];
    int base = blockIdx.x * 512;
    int i0 = base + 2 * threadIdx.x;
    int v0 = (i0 < N_NODES) ? cnt[i0] : 0;
    int v1 = (i0 + 1 < N_NODES) ? cnt[i0 + 1] : 0;
    int tsum = v0 + v1;
    s[threadIdx.x] = tsum;
    __syncthreads();
    for (int off = 1; off < 256; off <<= 1) {
        int val = (threadIdx.x >= off) ? s[threadIdx.x - off] : 0;
        __syncthreads();
        s[threadIdx.x] += val;
        __syncthreads();
    }
    int excl = s[threadIdx.x] - tsum;
    if (i0 < N_NODES) rp[i0] = excl;
    if (i0 + 1 < N_NODES) rp[i0 + 1] = excl + v0;
    if (threadIdx.x == 255) part[blockIdx.x] = s[255];
}

__global__ void k_scan2(int* __restrict__ part, int nb) {
    __shared__ int s[128];
    int t = threadIdx.x;
    int v = (t < nb) ? part[t] : 0;
    s[t] = v;
    __syncthreads();
    for (int off = 1; off < 128; off <<= 1) {
        int val = (t >= off) ? s[t - off] : 0;
        __syncthreads();
        s[t] += val;
        __syncthreads();
    }
    if (t < nb) part[t] = s[t] - v;  // exclusive
}

__global__ void k_scan3(int* __restrict__ rp, const int* __restrict__ part) {
    int add = part[blockIdx.x];
    int i0 = blockIdx.x * 512 + 2 * threadIdx.x;
    if (i0 < N_NODES) rp[i0] += add;
    if (i0 + 1 < N_NODES) rp[i0 + 1] += add;
    if (blockIdx.x == 0 && threadIdx.x == 0) rp[N_NODES] = N_EDGES;
}

__global__ void k_scatter(const int* __restrict__ row, const int* __restrict__ col,
                          const float* __restrict__ dis, const int* __restrict__ rp,
                          int* __restrict__ fill, int* __restrict__ cols,
                          float* __restrict__ wv) {
    int e = blockIdx.x * 256 + threadIdx.x;
    if (e < N_EDGES) {
        int r = row[e], c = col[e];
        int pos = rp[r] + atomicAdd(&fill[r], 1);
        cols[pos] = c;
        wv[pos] = -dis[r] * dis[c];
    }
}

// ---------------- SpMV: y = alpha * (L_hat @ h) + beta * z ----------------
// one wave per row; lane-per-feature (stride-64), coalesced row reads
template <int F>
__global__ void k_spmv(const int* __restrict__ rp, const int* __restrict__ cols,
                       const float* __restrict__ wv, const float* __restrict__ h,
                       const float* __restrict__ z, float alpha, float beta,
                       float* __restrict__ y) {
    int wave = threadIdx.x >> 6;
    int lane = threadIdx.x & 63;
    int r = blockIdx.x * 4 + wave;
    if (r >= N_NODES) return;
    int e0 = rp[r], e1 = rp[r + 1];
    constexpr int NF = F / 64;
    float acc[NF];
#pragma unroll
    for (int i = 0; i < NF; i++) acc[i] = 0.f;
    for (int e = e0; e < e1; e++) {
        int c = cols[e];
        float w = wv[e];
        const float* hp = h + (long)c * F + lane;
#pragma unroll
        for (int i = 0; i < NF; i++) acc[i] += w * hp[i * 64];
    }
    float* yp = y + (long)r * F + lane;
    if (beta != 0.f) {
        const float* zp = z + (long)r * F + lane;
#pragma unroll
        for (int i = 0; i < NF; i++) yp[i * 64] = alpha * acc[i] + beta * zp[i * 64];
    } else {
#pragma unroll
        for (int i = 0; i < NF; i++) yp[i * 64] = alpha * acc[i];
    }
}

// ---------------- fused 3-matrix GEMM: C = A0@W[0]+A1@W[1]+A2@W[2]+bias -------
// 128x64 tile, 256 threads, 8x4 micro-tile, K-chunk 16.
// LDS/FMA = 1.5 B (was 2.0 with 4x4) -> under the 256 B/clk LDS ceiling.
// As stride 132: write banks (4*lk+lm)%32 cover all 32 banks 2-way (free).
__global__ __launch_bounds__(256) void k_gemm3(
    const float* __restrict__ A0, const float* __restrict__ A1,
    const float* __restrict__ A2, const float* __restrict__ W,
    const float* __restrict__ bias, float* __restrict__ C, int Fin, int Fout) {
    __shared__ float As[16][132];  // [k][m]
    __shared__ float Bs[16][64];   // [k][n]
    int tid = threadIdx.x;
    int tx = tid & 15, ty = tid >> 4;
    int mBase = blockIdx.x * 128;
    int nBase = blockIdx.y * 64;
    const float* Aarr[3] = {A0, A1, A2};
    float acc[8][4] = {};
    int nChunks = (3 * Fin) / 16;
    int lm = tid >> 4;  // A-load row group 0..15
    int lk = tid & 15;  // k within chunk
    int bk = tid >> 6;  // B-load k group 0..3
    int bn = tid & 63;  // n
    for (int ch = 0; ch < nChunks; ch++) {
        int kg = ch * 16;
        int j = kg / Fin;
        int kk = kg % Fin;
        const float* A = Aarr[j];
        const float* Wj = W + ((long)j * Fin + kk) * Fout + nBase;
#pragma unroll
        for (int i = 0; i < 8; i++) {
            int m = mBase + lm + i * 16;
            As[lk][lm + i * 16] = (m < N_NODES) ? A[(long)m * Fin + kk + lk] : 0.f;
        }
#pragma unroll
        for (int i = 0; i < 4; i++) {
            int k = bk + i * 4;
            Bs[k][bn] = Wj[(long)k * Fout + bn];
        }
        __syncthreads();
#pragma unroll
        for (int k = 0; k < 16; k++) {
            float4 a0 = *(const float4*)&As[k][ty * 8];
            float4 a1 = *(const float4*)&As[k][ty * 8 + 4];
            float4 b4 = *(const float4*)&Bs[k][tx * 4];
            float av[8] = {a0.x, a0.y, a0.z, a0.w, a1.x, a1.y, a1.z, a1.w};
            float bv[4] = {b4.x, b4.y, b4.z, b4.w};
#pragma unroll
            for (int i = 0; i < 8; i++)
#pragma unroll
                for (int jj = 0; jj < 4; jj++) acc[i][jj] += av[i] * bv[jj];
        }
        __syncthreads();
    }
#pragma unroll
    for (int i = 0; i < 8; i++) {
        int m = mBase + ty * 8 + i;
        if (m < N_NODES) {
#pragma unroll
            for (int jj = 0; jj < 4; jj++) {
                int n = nBase + tx * 4 + jj;
                C[(long)m * Fout + n] = acc[i][jj] + bias[n];
            }
        }
    }
}

// ---------------- pooling: chunked partial sums + atomics ----------------
// 391 blocks x 128 threads; each block sums a 128-node chunk (coalesced),
// flushing per-graph partials. batch is sorted, so ~1-2 flushes per block.
__global__ void k_pool_partial(const float* __restrict__ h,
                               const int* __restrict__ batch,
                               float* __restrict__ psum, int* __restrict__ pcnt) {
    int f = threadIdx.x;  // 128
    int n0 = blockIdx.x * POOL_CHUNK;
    int n1 = n0 + POOL_CHUNK;
    if (n1 > N_NODES) n1 = N_NODES;
    if (n0 >= N_NODES) return;
    int curg = batch[n0];
    float acc = 0.f;
    int run = 0;
    for (int n = n0; n < n1; n++) {
        int g = batch[n];
        if (g != curg) {
            atomicAdd(&psum[curg * F_OUTT + f], acc);
            if (f == 0) atomicAdd(&pcnt[curg], run);
            acc = 0.f;
            run = 0;
            curg = g;
        }
        acc += h[(long)n * F_OUTT + f];
        run++;
    }
    atomicAdd(&psum[curg * F_OUTT + f], acc);
    if (f == 0) atomicAdd(&pcnt[curg], run);
}

__global__ void k_head(const float* __restrict__ psum, const int* __restrict__ pcnt,
                       const float* __restrict__ fcw, const float* __restrict__ fcb,
                       float* __restrict__ out) {
    int g = blockIdx.x;
    int c = threadIdx.x;  // 64 threads, lanes >= N_CLS idle
    __shared__ float sl[N_CLS];
    float inv = 1.f / fmaxf((float)pcnt[g], 1.f);
    float l = 0.f;
    if (c < N_CLS) {
        l = fcb[c];
        for (int k = 0; k < F_OUTT; k++)
            l += psum[g * F_OUTT + k] * inv * fcw[k * N_CLS + c];
        sl[c] = l;
    }
    __syncthreads();
    if (c < N_CLS) {
        float m = -1e30f;
        for (int i = 0; i < N_CLS; i++) m = fmaxf(m, sl[i]);
        float s = 0.f;
        for (int i = 0; i < N_CLS; i++) s += expf(sl[i] - m);
        out[g * N_CLS + c] = l - m - logf(s);
    }
}

extern "C" void kernel_launch(void* const* d_in, const int* in_sizes, int n_in,
                              void* d_out, int out_size, void* d_ws, size_t ws_size,
                              hipStream_t stream) {
    const float* x = (const float*)d_in[0];
    const int* ei = (const int*)d_in[1];
    const int* batch = (const int*)d_in[2];
    const float* W1 = (const float*)d_in[3];
    const float* b1 = (const float*)d_in[4];
    const float* W2 = (const float*)d_in[5];
    const float* b2 = (const float*)d_in[6];
    const float* W3 = (const float*)d_in[7];
    const float* b3 = (const float*)d_in[8];
    const float* fcw = (const float*)d_in[9];
    const float* fcb = (const float*)d_in[10];
    float* out = (float*)d_out;
    const int* row = ei;
    const int* col = ei + N_EDGES;

    char* p = (char*)d_ws;
    auto carve = [&](size_t bytes) {
        char* q = p;
        p += (bytes + 255) & ~(size_t)255;
        return q;
    };
    int* cnt = (int*)carve(N_NODES * 4);
    int* fill = (int*)carve(N_NODES * 4);
    float* dis = (float*)carve(N_NODES * 4);
    int* rp = (int*)carve((N_NODES + 1) * 4);
    int* part = (int*)carve(128 * 4);
    int* cols = (int*)carve((size_t)N_EDGES * 4);
    float* wv = (float*)carve((size_t)N_EDGES * 4);
    size_t hbytes = (size_t)N_NODES * 192 * 4;
    float* bufA = (float*)carve(hbytes);
    float* bufB = (float*)carve(hbytes);
    float* bufC = (float*)carve(hbytes);
    float* bufD = (float*)carve(hbytes);
    float* psum = (float*)carve(N_GRAPHS * F_OUTT * 4);
    int* pcnt = (int*)carve(N_GRAPHS * 4);

    hipMemsetAsync(cnt, 0, N_NODES * 4, stream);
    hipMemsetAsync(fill, 0, N_NODES * 4, stream);
    hipMemsetAsync(psum, 0, N_GRAPHS * F_OUTT * 4, stream);
    hipMemsetAsync(pcnt, 0, N_GRAPHS * 4, stream);

    k_deg<<<(N_EDGES + 255) / 256, 256, 0, stream>>>(row, cnt);
    k_dis<<<(N_NODES + 255) / 256, 256, 0, stream>>>(cnt, dis);
    int nb = (N_NODES + 511) / 512;  // 98
    k_scan1<<<nb, 256, 0, stream>>>(cnt, rp, part);
    k_scan2<<<1, 128, 0, stream>>>(part, nb);
    k_scan3<<<nb, 256, 0, stream>>>(rp, part);
    k_scatter<<<(N_EDGES + 255) / 256, 256, 0, stream>>>(row, col, dis, rp, fill, cols, wv);

    const int spmvGrid = (N_NODES + 3) / 4;  // 4 rows (waves) per block

    // Layer 1: in=x (128) -> out=bufA (192)
    k_spmv<128><<<spmvGrid, 256, 0, stream>>>(rp, cols, wv, x, x, 1.f, 0.f, bufB);
    k_spmv<128><<<spmvGrid, 256, 0, stream>>>(rp, cols, wv, bufB, x, 2.f, -1.f, bufC);
    {
        dim3 g((N_NODES + 127) / 128, 192 / 64);
        k_gemm3<<<g, 256, 0, stream>>>(x, bufB, bufC, W1, b1, bufA, 128, 192);
    }
    // Layer 2: in=bufA (192) -> out=bufD (192)
    k_spmv<192><<<spmvGrid, 256, 0, stream>>>(rp, cols, wv, bufA, bufA, 1.f, 0.f, bufB);
    k_spmv<192><<<spmvGrid, 256, 0, stream>>>(rp, cols, wv, bufB, bufA, 2.f, -1.f, bufC);
    {
        dim3 g((N_NODES + 127) / 128, 192 / 64);
        k_gemm3<<<g, 256, 0, stream>>>(bufA, bufB, bufC, W2, b2, bufD, 192, 192);
    }
    // Layer 3: in=bufD (192) -> out=bufA (128)
    k_spmv<192><<<spmvGrid, 256, 0, stream>>>(rp, cols, wv, bufD, bufD, 1.f, 0.f, bufB);
    k_spmv<192><<<spmvGrid, 256, 0, stream>>>(rp, cols, wv, bufB, bufD, 2.f, -1.f, bufC);
    {
        dim3 g((N_NODES + 127) / 128, 128 / 64);
        k_gemm3<<<g, 256, 0, stream>>>(bufD, bufB, bufC, W3, b3, bufA, 192, 128);
    }

    k_pool_partial<<<(N_NODES + POOL_CHUNK - 1) / POOL_CHUNK, F_OUTT, 0, stream>>>(
        bufA, batch, psum, pcnt);
    k_head<<<N_GRAPHS, 64, 0, stream>>>(psum, pcnt, fcw, fcb, out);
}

// Round 3
// 816.442 us; speedup vs baseline: 1.6994x; 1.6051x over previous
//
#include <hip/hip_runtime.h>
#include <math.h>

#define N_NODES 50000
#define N_EDGES 800000
#define N_GRAPHS 64
#define F_INN 128
#define F_HID 192
#define F_OUTT 128
#define N_CLS 10
#define POOL_CHUNK 128

typedef short short8 __attribute__((ext_vector_type(8)));
typedef float f32x4 __attribute__((ext_vector_type(4)));

static __device__ inline unsigned short f2bf(float f) {
    unsigned int u = __float_as_uint(f);
    unsigned int r = (u + 0x7FFFu + ((u >> 16) & 1u)) >> 16;  // RNE
    return (unsigned short)r;
}
static __device__ inline float bf2f(unsigned short h) {
    return __uint_as_float(((unsigned int)h) << 16);
}

// ---------------- CSR build ----------------
__global__ void k_deg(const int* __restrict__ row, int* __restrict__ cnt) {
    int e = blockIdx.x * 256 + threadIdx.x;
    if (e < N_EDGES) atomicAdd(&cnt[row[e]], 1);
}

__global__ void k_dis(const int* __restrict__ cnt, float* __restrict__ dis) {
    int i = blockIdx.x * 256 + threadIdx.x;
    if (i < N_NODES) {
        int d = cnt[i];
        dis[i] = d > 0 ? rsqrtf((float)d) : 0.f;
    }
}

__global__ void k_scan1(const int* __restrict__ cnt, int* __restrict__ rp,
                        int* __restrict__ part) {
    __shared__ int s[256];
    int base = blockIdx.x * 512;
    int i0 = base + 2 * threadIdx.x;
    int v0 = (i0 < N_NODES) ? cnt[i0] : 0;
    int v1 = (i0 + 1 < N_NODES) ? cnt[i0 + 1] : 0;
    int tsum = v0 + v1;
    s[threadIdx.x] = tsum;
    __syncthreads();
    for (int off = 1; off < 256; off <<= 1) {
        int val = (threadIdx.x >= off) ? s[threadIdx.x - off] : 0;
        __syncthreads();
        s[threadIdx.x] += val;
        __syncthreads();
    }
    int excl = s[threadIdx.x] - tsum;
    if (i0 < N_NODES) rp[i0] = excl;
    if (i0 + 1 < N_NODES) rp[i0 + 1] = excl + v0;
    if (threadIdx.x == 255) part[blockIdx.x] = s[255];
}

__global__ void k_scan2(int* __restrict__ part, int nb) {
    __shared__ int s[128];
    int t = threadIdx.x;
    int v = (t < nb) ? part[t] : 0;
    s[t] = v;
    __syncthreads();
    for (int off = 1; off < 128; off <<= 1) {
        int val = (t >= off) ? s[t - off] : 0;
        __syncthreads();
        s[t] += val;
        __syncthreads();
    }
    if (t < nb) part[t] = s[t] - v;  // exclusive
}

__global__ void k_scan3(int* __restrict__ rp, const int* __restrict__ part) {
    int add = part[blockIdx.x];
    int i0 = blockIdx.x * 512 + 2 * threadIdx.x;
    if (i0 < N_NODES) rp[i0] += add;
    if (i0 + 1 < N_NODES) rp[i0 + 1] += add;
    if (blockIdx.x == 0 && threadIdx.x == 0) rp[N_NODES] = N_EDGES;
}

// packed CSR payload: (col, weight-bits)
__global__ void k_scatter(const int* __restrict__ row, const int* __restrict__ col,
                          const float* __restrict__ dis, const int* __restrict__ rp,
                          int* __restrict__ fill, int2* __restrict__ cw) {
    int e = blockIdx.x * 256 + threadIdx.x;
    if (e < N_EDGES) {
        int r = row[e], c = col[e];
        int pos = rp[r] + atomicAdd(&fill[r], 1);
        int2 v;
        v.x = c;
        v.y = __float_as_int(-dis[r] * dis[c]);
        cw[pos] = v;
    }
}

// ---------------- conversions ----------------
__global__ void k_convX(const float* __restrict__ x, unsigned short* __restrict__ xb,
                        int n) {
    int i = blockIdx.x * 256 + threadIdx.x;
    if (i < n) xb[i] = f2bf(x[i]);
}

// W[j][k][n] fp32 -> Wt[j][n][k] bf16
__global__ void k_convW(const float* __restrict__ W, unsigned short* __restrict__ Wt,
                        int Fin, int Fout) {
    int idx = blockIdx.x * 256 + threadIdx.x;
    int per = Fin * Fout;
    if (idx < 3 * per) {
        int j = idx / per;
        int r = idx - j * per;
        int k = r / Fout;
        int n = r - k * Fout;
        Wt[j * per + n * Fin + k] = f2bf(W[idx]);
    }
}

// ---------------- SpMV (bf16 in/out, fp32 accum) ----------------
// y = alpha * (L_hat @ h) + beta * z ; one wave per row, lane-per-feature
template <int F>
__global__ void k_spmv(const int* __restrict__ rp, const int2* __restrict__ cw,
                       const unsigned short* __restrict__ h,
                       const unsigned short* __restrict__ z, float alpha, float beta,
                       unsigned short* __restrict__ y) {
    int wave = threadIdx.x >> 6;
    int lane = threadIdx.x & 63;
    int r = blockIdx.x * 4 + wave;
    if (r >= N_NODES) return;
    int e0 = rp[r], e1 = rp[r + 1];
    constexpr int NF = F / 64;
    float acc[NF];
#pragma unroll
    for (int i = 0; i < NF; i++) acc[i] = 0.f;
    for (int e = e0; e < e1; e++) {
        int2 p = cw[e];
        float w = __int_as_float(p.y);
        const unsigned short* hp = h + (size_t)p.x * F + lane;
#pragma unroll
        for (int i = 0; i < NF; i++) acc[i] += w * bf2f(hp[i * 64]);
    }
    unsigned short* yp = y + (size_t)r * F + lane;
    if (beta != 0.f) {
        const unsigned short* zp = z + (size_t)r * F + lane;
#pragma unroll
        for (int i = 0; i < NF; i++)
            yp[i * 64] = f2bf(alpha * acc[i] + beta * bf2f(zp[i * 64]));
    } else {
#pragma unroll
        for (int i = 0; i < NF; i++) yp[i * 64] = f2bf(alpha * acc[i]);
    }
}

// ---------------- fused 3-matrix bf16 MFMA GEMM ----------------
// C = A0@W[0]+A1@W[1]+A2@W[2]+bias, A row-major [M][Fin] bf16,
// Wt pre-transposed [3][Fout][Fin] bf16, C bf16 [M][Fout].
// Block: 256 thr = 4 waves; tile M=128 x N=64; wave = 32 rows x 64 cols
// = 2x4 grid of 16x16x32 MFMAs. LDS stride 40 shorts breaks pow-2 conflicts.
__global__ __launch_bounds__(256) void k_gemm3(
    const unsigned short* __restrict__ A0, const unsigned short* __restrict__ A1,
    const unsigned short* __restrict__ A2, const unsigned short* __restrict__ Wt,
    const float* __restrict__ bias, unsigned short* __restrict__ C, int Fin,
    int Fout) {
    __shared__ unsigned short As[128 * 40];
    __shared__ unsigned short Bs[64 * 40];
    int t = threadIdx.x;
    int w = t >> 6;
    int lane = t & 63;
    int ml = lane & 15;
    int quad = lane >> 4;
    int mBase = blockIdx.x * 128;
    int nBase = blockIdx.y * 64;
    int per = Fin * Fout;

    f32x4 acc[2][4];
#pragma unroll
    for (int i = 0; i < 2; i++)
#pragma unroll
        for (int jn = 0; jn < 4; jn++) acc[i][jn] = (f32x4){0.f, 0.f, 0.f, 0.f};

    // staging indices
    int srow = t >> 2;      // 0..63
    int schunk = t & 3;     // 16B chunk within 32-k slab
    int nChunks = (3 * Fin) >> 5;

    for (int ch = 0; ch < nChunks; ch++) {
        int kg = ch << 5;
        int j = kg / Fin;
        int kk = kg - j * Fin;
        const unsigned short* Aj = (j == 0) ? A0 : (j == 1) ? A1 : A2;
        if (ch > 0) __syncthreads();  // protect LDS from previous iter's readers
#pragma unroll
        for (int pass = 0; pass < 2; pass++) {
            int row = srow + pass * 64;
            int gm = mBase + row;
            uint4 v = {0u, 0u, 0u, 0u};
            if (gm < N_NODES)
                v = *(const uint4*)(Aj + (size_t)gm * Fin + kk + schunk * 8);
            *(uint4*)&As[row * 40 + schunk * 8] = v;
        }
        {
            const unsigned short* src =
                Wt + (size_t)j * per + (size_t)(nBase + srow) * Fin + kk + schunk * 8;
            *(uint4*)&Bs[srow * 40 + schunk * 8] = *(const uint4*)src;
        }
        __syncthreads();

        short8 afr[2], bfr[4];
#pragma unroll
        for (int i = 0; i < 2; i++)
            afr[i] = *(const short8*)&As[(w * 32 + i * 16 + ml) * 40 + quad * 8];
#pragma unroll
        for (int jn = 0; jn < 4; jn++)
            bfr[jn] = *(const short8*)&Bs[(jn * 16 + ml) * 40 + quad * 8];
#pragma unroll
        for (int i = 0; i < 2; i++)
#pragma unroll
            for (int jn = 0; jn < 4; jn++)
                acc[i][jn] = __builtin_amdgcn_mfma_f32_16x16x32_bf16(
                    afr[i], bfr[jn], acc[i][jn], 0, 0, 0);
    }

    float biasv[4];
#pragma unroll
    for (int jn = 0; jn < 4; jn++) biasv[jn] = bias[nBase + jn * 16 + ml];

#pragma unroll
    for (int i = 0; i < 2; i++) {
#pragma unroll
        for (int r = 0; r < 4; r++) {
            int m = mBase + w * 32 + i * 16 + quad * 4 + r;
            if (m < N_NODES) {
                unsigned short* cp = C + (size_t)m * Fout + nBase + ml;
#pragma unroll
                for (int jn = 0; jn < 4; jn++)
                    cp[jn * 16] = f2bf(acc[i][jn][r] + biasv[jn]);
            }
        }
    }
}

// ---------------- pooling: chunked partial sums + atomics ----------------
__global__ void k_pool_partial(const unsigned short* __restrict__ h,
                               const int* __restrict__ batch,
                               float* __restrict__ psum, int* __restrict__ pcnt) {
    int f = threadIdx.x;  // 128
    int n0 = blockIdx.x * POOL_CHUNK;
    int n1 = n0 + POOL_CHUNK;
    if (n1 > N_NODES) n1 = N_NODES;
    if (n0 >= N_NODES) return;
    int curg = batch[n0];
    float acc = 0.f;
    int run = 0;
    for (int n = n0; n < n1; n++) {
        int g = batch[n];
        if (g != curg) {
            atomicAdd(&psum[curg * F_OUTT + f], acc);
            if (f == 0) atomicAdd(&pcnt[curg], run);
            acc = 0.f;
            run = 0;
            curg = g;
        }
        acc += bf2f(h[(size_t)n * F_OUTT + f]);
        run++;
    }
    atomicAdd(&psum[curg * F_OUTT + f], acc);
    if (f == 0) atomicAdd(&pcnt[curg], run);
}

__global__ void k_head(const float* __restrict__ psum, const int* __restrict__ pcnt,
                       const float* __restrict__ fcw, const float* __restrict__ fcb,
                       float* __restrict__ out) {
    int g = blockIdx.x;
    int c = threadIdx.x;  // 64 threads, lanes >= N_CLS idle
    __shared__ float sl[N_CLS];
    float inv = 1.f / fmaxf((float)pcnt[g], 1.f);
    float l = 0.f;
    if (c < N_CLS) {
        l = fcb[c];
        for (int k = 0; k < F_OUTT; k++)
            l += psum[g * F_OUTT + k] * inv * fcw[k * N_CLS + c];
        sl[c] = l;
    }
    __syncthreads();
    if (c < N_CLS) {
        float m = -1e30f;
        for (int i = 0; i < N_CLS; i++) m = fmaxf(m, sl[i]);
        float s = 0.f;
        for (int i = 0; i < N_CLS; i++) s += expf(sl[i] - m);
        out[g * N_CLS + c] = l - m - logf(s);
    }
}

extern "C" void kernel_launch(void* const* d_in, const int* in_sizes, int n_in,
                              void* d_out, int out_size, void* d_ws, size_t ws_size,
                              hipStream_t stream) {
    const float* x = (const float*)d_in[0];
    const int* ei = (const int*)d_in[1];
    const int* batch = (const int*)d_in[2];
    const float* W1 = (const float*)d_in[3];
    const float* b1 = (const float*)d_in[4];
    const float* W2 = (const float*)d_in[5];
    const float* b2 = (const float*)d_in[6];
    const float* W3 = (const float*)d_in[7];
    const float* b3 = (const float*)d_in[8];
    const float* fcw = (const float*)d_in[9];
    const float* fcb = (const float*)d_in[10];
    float* out = (float*)d_out;
    const int* row = ei;
    const int* col = ei + N_EDGES;

    char* p = (char*)d_ws;
    auto carve = [&](size_t bytes) {
        char* q = p;
        p += (bytes + 255) & ~(size_t)255;
        return q;
    };
    int* cnt = (int*)carve(N_NODES * 4);
    int* fill = (int*)carve(N_NODES * 4);
    float* dis = (float*)carve(N_NODES * 4);
    int* rp = (int*)carve((N_NODES + 1) * 4);
    int* part = (int*)carve(128 * 4);
    int2* cw = (int2*)carve((size_t)N_EDGES * 8);
    unsigned short* xb = (unsigned short*)carve((size_t)N_NODES * F_INN * 2);
    size_t hbytes = (size_t)N_NODES * 192 * 2;
    unsigned short* bufA = (unsigned short*)carve(hbytes);
    unsigned short* bufB = (unsigned short*)carve(hbytes);
    unsigned short* bufC = (unsigned short*)carve(hbytes);
    unsigned short* bufD = (unsigned short*)carve(hbytes);
    unsigned short* Wt1 = (unsigned short*)carve(3 * 128 * 192 * 2);
    unsigned short* Wt2 = (unsigned short*)carve(3 * 192 * 192 * 2);
    unsigned short* Wt3 = (unsigned short*)carve(3 * 192 * 128 * 2);
    float* psum = (float*)carve(N_GRAPHS * F_OUTT * 4);
    int* pcnt = (int*)carve(N_GRAPHS * 4);

    hipMemsetAsync(cnt, 0, N_NODES * 4, stream);
    hipMemsetAsync(fill, 0, N_NODES * 4, stream);
    hipMemsetAsync(psum, 0, N_GRAPHS * F_OUTT * 4, stream);
    hipMemsetAsync(pcnt, 0, N_GRAPHS * 4, stream);

    k_deg<<<(N_EDGES + 255) / 256, 256, 0, stream>>>(row, cnt);
    k_dis<<<(N_NODES + 255) / 256, 256, 0, stream>>>(cnt, dis);
    int nb = (N_NODES + 511) / 512;  // 98
    k_scan1<<<nb, 256, 0, stream>>>(cnt, rp, part);
    k_scan2<<<1, 128, 0, stream>>>(part, nb);
    k_scan3<<<nb, 256, 0, stream>>>(rp, part);
    k_scatter<<<(N_EDGES + 255) / 256, 256, 0, stream>>>(row, col, dis, rp, fill, cw);

    k_convX<<<(N_NODES * F_INN + 255) / 256, 256, 0, stream>>>(x, xb, N_NODES * F_INN);
    k_convW<<<(3 * 128 * 192 + 255) / 256, 256, 0, stream>>>(W1, Wt1, 128, 192);
    k_convW<<<(3 * 192 * 192 + 255) / 256, 256, 0, stream>>>(W2, Wt2, 192, 192);
    k_convW<<<(3 * 192 * 128 + 255) / 256, 256, 0, stream>>>(W3, Wt3, 192, 128);

    const int spmvGrid = (N_NODES + 3) / 4;

    // Layer 1: in=xb (128) -> out=bufA (192)
    k_spmv<128><<<spmvGrid, 256, 0, stream>>>(rp, cw, xb, xb, 1.f, 0.f, bufB);
    k_spmv<128><<<spmvGrid, 256, 0, stream>>>(rp, cw, bufB, xb, 2.f, -1.f, bufC);
    {
        dim3 g((N_NODES + 127) / 128, 192 / 64);
        k_gemm3<<<g, 256, 0, stream>>>(xb, bufB, bufC, Wt1, b1, bufA, 128, 192);
    }
    // Layer 2: in=bufA (192) -> out=bufD (192)
    k_spmv<192><<<spmvGrid, 256, 0, stream>>>(rp, cw, bufA, bufA, 1.f, 0.f, bufB);
    k_spmv<192><<<spmvGrid, 256, 0, stream>>>(rp, cw, bufB, bufA, 2.f, -1.f, bufC);
    {
        dim3 g((N_NODES + 127) / 128, 192 / 64);
        k_gemm3<<<g, 256, 0, stream>>>(bufA, bufB, bufC, Wt2, b2, bufD, 192, 192);
    }
    // Layer 3: in=bufD (192) -> out=bufA (128)
    k_spmv<192><<<spmvGrid, 256, 0, stream>>>(rp, cw, bufD, bufD, 1.f, 0.f, bufB);
    k_spmv<192><<<spmvGrid, 256, 0, stream>>>(rp, cw, bufB, bufD, 2.f, -1.f, bufC);
    {
        dim3 g((N_NODES + 127) / 128, 128 / 64);
        k_gemm3<<<g, 256, 0, stream>>>(bufD, bufB, bufC, Wt3, b3, bufA, 192, 128);
    }

    k_pool_partial<<<(N_NODES + POOL_CHUNK - 1) / POOL_CHUNK, F_OUTT, 0, stream>>>(
        bufA, batch, psum, pcnt);
    k_head<<<N_GRAPHS, 64, 0, stream>>>(psum, pcnt, fcw, fcb, out);
}

// Round 4
// 572.794 us; speedup vs baseline: 2.4223x; 1.4254x over previous
//
#include <hip/hip_runtime.h>
#include <math.h>

#define N_NODES 50000
#define N_EDGES 800000
#define N_GRAPHS 64
#define F_INN 128
#define F_HID 192
#define F_OUTT 128
#define N_CLS 10
#define POOL_CHUNK 128

typedef short short8 __attribute__((ext_vector_type(8)));
typedef float f32x4 __attribute__((ext_vector_type(4)));

static __device__ inline unsigned short f2bf(float f) {
    unsigned int u = __float_as_uint(f);
    unsigned int r = (u + 0x7FFFu + ((u >> 16) & 1u)) >> 16;  // RNE
    return (unsigned short)r;
}
static __device__ inline float bf2f(unsigned short h) {
    return __uint_as_float(((unsigned int)h) << 16);
}

// ---------------- CSR build ----------------
__global__ void k_deg(const int* __restrict__ row, int* __restrict__ cnt) {
    int e = blockIdx.x * 256 + threadIdx.x;
    if (e < N_EDGES) atomicAdd(&cnt[row[e]], 1);
}

// scan phase 1 + fused dis = rsqrt(deg)
__global__ void k_scan1(const int* __restrict__ cnt, int* __restrict__ rp,
                        int* __restrict__ part, float* __restrict__ dis) {
    __shared__ int s[256];
    int base = blockIdx.x * 512;
    int i0 = base + 2 * threadIdx.x;
    int v0 = (i0 < N_NODES) ? cnt[i0] : 0;
    int v1 = (i0 + 1 < N_NODES) ? cnt[i0 + 1] : 0;
    if (i0 < N_NODES) dis[i0] = v0 > 0 ? rsqrtf((float)v0) : 0.f;
    if (i0 + 1 < N_NODES) dis[i0 + 1] = v1 > 0 ? rsqrtf((float)v1) : 0.f;
    int tsum = v0 + v1;
    s[threadIdx.x] = tsum;
    __syncthreads();
    for (int off = 1; off < 256; off <<= 1) {
        int val = (threadIdx.x >= off) ? s[threadIdx.x - off] : 0;
        __syncthreads();
        s[threadIdx.x] += val;
        __syncthreads();
    }
    int excl = s[threadIdx.x] - tsum;
    if (i0 < N_NODES) rp[i0] = excl;
    if (i0 + 1 < N_NODES) rp[i0 + 1] = excl + v0;
    if (threadIdx.x == 255) part[blockIdx.x] = s[255];
}

__global__ void k_scan2(int* __restrict__ part, int nb) {
    __shared__ int s[128];
    int t = threadIdx.x;
    int v = (t < nb) ? part[t] : 0;
    s[t] = v;
    __syncthreads();
    for (int off = 1; off < 128; off <<= 1) {
        int val = (t >= off) ? s[t - off] : 0;
        __syncthreads();
        s[t] += val;
        __syncthreads();
    }
    if (t < nb) part[t] = s[t] - v;  // exclusive
}

__global__ void k_scan3(int* __restrict__ rp, const int* __restrict__ part) {
    int add = part[blockIdx.x];
    int i0 = blockIdx.x * 512 + 2 * threadIdx.x;
    if (i0 < N_NODES) rp[i0] += add;
    if (i0 + 1 < N_NODES) rp[i0 + 1] += add;
    if (blockIdx.x == 0 && threadIdx.x == 0) rp[N_NODES] = N_EDGES;
}

// packed CSR payload: (col, weight-bits)
__global__ void k_scatter(const int* __restrict__ row, const int* __restrict__ col,
                          const float* __restrict__ dis, const int* __restrict__ rp,
                          int* __restrict__ fill, int2* __restrict__ cw) {
    int e = blockIdx.x * 256 + threadIdx.x;
    if (e < N_EDGES) {
        int r = row[e], c = col[e];
        int pos = rp[r] + atomicAdd(&fill[r], 1);
        int2 v;
        v.x = c;
        v.y = __float_as_int(-dis[r] * dis[c]);
        cw[pos] = v;
    }
}

// ---------------- fused fp32->bf16 conversions (x + 3 transposed W) --------
#define NX (N_NODES * F_INN)
#define NW1 (3 * 128 * 192)
#define NW2 (3 * 192 * 192)
#define NW3 (3 * 192 * 128)
__global__ void k_convAll(const float* __restrict__ x, const float* __restrict__ W1,
                          const float* __restrict__ W2, const float* __restrict__ W3,
                          unsigned short* __restrict__ xb,
                          unsigned short* __restrict__ Wt1,
                          unsigned short* __restrict__ Wt2,
                          unsigned short* __restrict__ Wt3) {
    int idx = blockIdx.x * 256 + threadIdx.x;
    if (idx < NX) {
        xb[idx] = f2bf(x[idx]);
        return;
    }
    idx -= NX;
    if (idx < NW1) {  // W1[j][k][n] -> Wt1[j][n][k], Fin=128, Fout=192
        int per = 128 * 192;
        int j = idx / per, r = idx - j * per;
        int k = r / 192, n = r - k * 192;
        Wt1[j * per + n * 128 + k] = f2bf(W1[idx]);
        return;
    }
    idx -= NW1;
    if (idx < NW2) {  // Fin=192, Fout=192
        int per = 192 * 192;
        int j = idx / per, r = idx - j * per;
        int k = r / 192, n = r - k * 192;
        Wt2[j * per + n * 192 + k] = f2bf(W2[idx]);
        return;
    }
    idx -= NW2;
    if (idx < NW3) {  // Fin=192, Fout=128
        int per = 192 * 128;
        int j = idx / per, r = idx - j * per;
        int k = r / 128, n = r - k * 128;
        Wt3[j * per + n * 192 + k] = f2bf(W3[idx]);
    }
}

// ---------------- SpMV (bf16 in/out, fp32 accum) ----------------
// y = alpha*(L_hat@h) + beta*z. One wave per row. Lane l owns feats
// {2l, 2l+1} via one packed uint gather (+ feat 128+l via ushort for F=192).
// Edge loop unrolled x4 with batched loads: 4 latency chains overlap.
template <int F>
__global__ void k_spmv(const int* __restrict__ rp, const int2* __restrict__ cw,
                       const unsigned short* __restrict__ h,
                       const unsigned short* __restrict__ z, float alpha, float beta,
                       unsigned short* __restrict__ y) {
    constexpr bool EX = (F > 128);
    int wave = threadIdx.x >> 6;
    int lane = threadIdx.x & 63;
    int r = blockIdx.x * 4 + wave;
    if (r >= N_NODES) return;
    int e0 = rp[r], e1 = rp[r + 1];
    float a0 = 0.f, a1 = 0.f, a2 = 0.f;
    int e = e0;
    for (; e + 4 <= e1; e += 4) {
        int2 p0 = cw[e], p1 = cw[e + 1], p2 = cw[e + 2], p3 = cw[e + 3];
        unsigned int g0 = ((const unsigned int*)(h + (size_t)p0.x * F))[lane];
        unsigned int g1 = ((const unsigned int*)(h + (size_t)p1.x * F))[lane];
        unsigned int g2 = ((const unsigned int*)(h + (size_t)p2.x * F))[lane];
        unsigned int g3 = ((const unsigned int*)(h + (size_t)p3.x * F))[lane];
        unsigned short s0 = 0, s1 = 0, s2 = 0, s3 = 0;
        if constexpr (EX) {
            s0 = h[(size_t)p0.x * F + 128 + lane];
            s1 = h[(size_t)p1.x * F + 128 + lane];
            s2 = h[(size_t)p2.x * F + 128 + lane];
            s3 = h[(size_t)p3.x * F + 128 + lane];
        }
        float w0 = __int_as_float(p0.y), w1 = __int_as_float(p1.y);
        float w2 = __int_as_float(p2.y), w3 = __int_as_float(p3.y);
        a0 += w0 * bf2f((unsigned short)g0);
        a1 += w0 * bf2f((unsigned short)(g0 >> 16));
        a0 += w1 * bf2f((unsigned short)g1);
        a1 += w1 * bf2f((unsigned short)(g1 >> 16));
        a0 += w2 * bf2f((unsigned short)g2);
        a1 += w2 * bf2f((unsigned short)(g2 >> 16));
        a0 += w3 * bf2f((unsigned short)g3);
        a1 += w3 * bf2f((unsigned short)(g3 >> 16));
        if constexpr (EX) {
            a2 += w0 * bf2f(s0) + w1 * bf2f(s1) + w2 * bf2f(s2) + w3 * bf2f(s3);
        }
    }
    for (; e < e1; e++) {
        int2 p = cw[e];
        unsigned int g = ((const unsigned int*)(h + (size_t)p.x * F))[lane];
        float w = __int_as_float(p.y);
        a0 += w * bf2f((unsigned short)g);
        a1 += w * bf2f((unsigned short)(g >> 16));
        if constexpr (EX) a2 += w * bf2f(h[(size_t)p.x * F + 128 + lane]);
    }
    float v0 = alpha * a0, v1 = alpha * a1, v2 = alpha * a2;
    if (beta != 0.f) {
        unsigned int zg = ((const unsigned int*)(z + (size_t)r * F))[lane];
        v0 += beta * bf2f((unsigned short)zg);
        v1 += beta * bf2f((unsigned short)(zg >> 16));
        if constexpr (EX) v2 += beta * bf2f(z[(size_t)r * F + 128 + lane]);
    }
    ((unsigned int*)(y + (size_t)r * F))[lane] =
        (unsigned int)f2bf(v0) | ((unsigned int)f2bf(v1) << 16);
    if constexpr (EX) y[(size_t)r * F + 128 + lane] = f2bf(v2);
}

// ---------------- fused 3-matrix bf16 MFMA GEMM ----------------
// C = A0@W[0]+A1@W[1]+A2@W[2]+bias, A row-major [M][Fin] bf16,
// Wt pre-transposed [3][Fout][Fin] bf16, C bf16 [M][Fout].
// Block: 256 thr = 4 waves; tile M=128 x N=64; wave = 32 rows x 64 cols
// = 2x4 grid of 16x16x32 MFMAs. LDS stride 40 shorts breaks pow-2 conflicts.
__global__ __launch_bounds__(256) void k_gemm3(
    const unsigned short* __restrict__ A0, const unsigned short* __restrict__ A1,
    const unsigned short* __restrict__ A2, const unsigned short* __restrict__ Wt,
    const float* __restrict__ bias, unsigned short* __restrict__ C, int Fin,
    int Fout) {
    __shared__ unsigned short As[128 * 40];
    __shared__ unsigned short Bs[64 * 40];
    int t = threadIdx.x;
    int w = t >> 6;
    int lane = t & 63;
    int ml = lane & 15;
    int quad = lane >> 4;
    int mBase = blockIdx.x * 128;
    int nBase = blockIdx.y * 64;
    int per = Fin * Fout;

    f32x4 acc[2][4];
#pragma unroll
    for (int i = 0; i < 2; i++)
#pragma unroll
        for (int jn = 0; jn < 4; jn++) acc[i][jn] = (f32x4){0.f, 0.f, 0.f, 0.f};

    int srow = t >> 2;   // 0..63
    int schunk = t & 3;  // 16B chunk within 32-k slab
    int nChunks = (3 * Fin) >> 5;

    for (int ch = 0; ch < nChunks; ch++) {
        int kg = ch << 5;
        int j = kg / Fin;
        int kk = kg - j * Fin;
        const unsigned short* Aj = (j == 0) ? A0 : (j == 1) ? A1 : A2;
        if (ch > 0) __syncthreads();
#pragma unroll
        for (int pass = 0; pass < 2; pass++) {
            int row = srow + pass * 64;
            int gm = mBase + row;
            uint4 v = {0u, 0u, 0u, 0u};
            if (gm < N_NODES)
                v = *(const uint4*)(Aj + (size_t)gm * Fin + kk + schunk * 8);
            *(uint4*)&As[row * 40 + schunk * 8] = v;
        }
        {
            const unsigned short* src =
                Wt + (size_t)j * per + (size_t)(nBase + srow) * Fin + kk + schunk * 8;
            *(uint4*)&Bs[srow * 40 + schunk * 8] = *(const uint4*)src;
        }
        __syncthreads();

        short8 afr[2], bfr[4];
#pragma unroll
        for (int i = 0; i < 2; i++)
            afr[i] = *(const short8*)&As[(w * 32 + i * 16 + ml) * 40 + quad * 8];
#pragma unroll
        for (int jn = 0; jn < 4; jn++)
            bfr[jn] = *(const short8*)&Bs[(jn * 16 + ml) * 40 + quad * 8];
#pragma unroll
        for (int i = 0; i < 2; i++)
#pragma unroll
            for (int jn = 0; jn < 4; jn++)
                acc[i][jn] = __builtin_amdgcn_mfma_f32_16x16x32_bf16(
                    afr[i], bfr[jn], acc[i][jn], 0, 0, 0);
    }

    float biasv[4];
#pragma unroll
    for (int jn = 0; jn < 4; jn++) biasv[jn] = bias[nBase + jn * 16 + ml];

#pragma unroll
    for (int i = 0; i < 2; i++) {
#pragma unroll
        for (int r = 0; r < 4; r++) {
            int m = mBase + w * 32 + i * 16 + quad * 4 + r;
            if (m < N_NODES) {
                unsigned short* cp = C + (size_t)m * Fout + nBase + ml;
#pragma unroll
                for (int jn = 0; jn < 4; jn++)
                    cp[jn * 16] = f2bf(acc[i][jn][r] + biasv[jn]);
            }
        }
    }
}

// ---------------- pooling: chunked partial sums + atomics ----------------
__global__ void k_pool_partial(const unsigned short* __restrict__ h,
                               const int* __restrict__ batch,
                               float* __restrict__ psum, int* __restrict__ pcnt) {
    int f = threadIdx.x;  // 128
    int n0 = blockIdx.x * POOL_CHUNK;
    int n1 = n0 + POOL_CHUNK;
    if (n1 > N_NODES) n1 = N_NODES;
    if (n0 >= N_NODES) return;
    int curg = batch[n0];
    float acc = 0.f;
    int run = 0;
    for (int n = n0; n < n1; n++) {
        int g = batch[n];
        if (g != curg) {
            atomicAdd(&psum[curg * F_OUTT + f], acc);
            if (f == 0) atomicAdd(&pcnt[curg], run);
            acc = 0.f;
            run = 0;
            curg = g;
        }
        acc += bf2f(h[(size_t)n * F_OUTT + f]);
        run++;
    }
    atomicAdd(&psum[curg * F_OUTT + f], acc);
    if (f == 0) atomicAdd(&pcnt[curg], run);
}

__global__ void k_head(const float* __restrict__ psum, const int* __restrict__ pcnt,
                       const float* __restrict__ fcw, const float* __restrict__ fcb,
                       float* __restrict__ out) {
    int g = blockIdx.x;
    int c = threadIdx.x;  // 64 threads, lanes >= N_CLS idle
    __shared__ float sl[N_CLS];
    float inv = 1.f / fmaxf((float)pcnt[g], 1.f);
    float l = 0.f;
    if (c < N_CLS) {
        l = fcb[c];
        for (int k = 0; k < F_OUTT; k++)
            l += psum[g * F_OUTT + k] * inv * fcw[k * N_CLS + c];
        sl[c] = l;
    }
    __syncthreads();
    if (c < N_CLS) {
        float m = -1e30f;
        for (int i = 0; i < N_CLS; i++) m = fmaxf(m, sl[i]);
        float s = 0.f;
        for (int i = 0; i < N_CLS; i++) s += expf(sl[i] - m);
        out[g * N_CLS + c] = l - m - logf(s);
    }
}

extern "C" void kernel_launch(void* const* d_in, const int* in_sizes, int n_in,
                              void* d_out, int out_size, void* d_ws, size_t ws_size,
                              hipStream_t stream) {
    const float* x = (const float*)d_in[0];
    const int* ei = (const int*)d_in[1];
    const int* batch = (const int*)d_in[2];
    const float* W1 = (const float*)d_in[3];
    const float* b1 = (const float*)d_in[4];
    const float* W2 = (const float*)d_in[5];
    const float* b2 = (const float*)d_in[6];
    const float* W3 = (const float*)d_in[7];
    const float* b3 = (const float*)d_in[8];
    const float* fcw = (const float*)d_in[9];
    const float* fcb = (const float*)d_in[10];
    float* out = (float*)d_out;
    const int* row = ei;
    const int* col = ei + N_EDGES;

    char* p = (char*)d_ws;
    auto carve = [&](size_t bytes) {
        char* q = p;
        p += (bytes + 255) & ~(size_t)255;
        return q;
    };
    int* cnt = (int*)carve(N_NODES * 4);
    int* fill = (int*)carve(N_NODES * 4);
    float* dis = (float*)carve(N_NODES * 4);
    int* rp = (int*)carve((N_NODES + 1) * 4);
    int* part = (int*)carve(128 * 4);
    int2* cw = (int2*)carve((size_t)N_EDGES * 8);
    unsigned short* xb = (unsigned short*)carve((size_t)N_NODES * F_INN * 2);
    size_t hbytes = (size_t)N_NODES * 192 * 2;
    unsigned short* bufA = (unsigned short*)carve(hbytes);
    unsigned short* bufB = (unsigned short*)carve(hbytes);
    unsigned short* bufC = (unsigned short*)carve(hbytes);
    unsigned short* bufD = (unsigned short*)carve(hbytes);
    unsigned short* Wt1 = (unsigned short*)carve(NW1 * 2);
    unsigned short* Wt2 = (unsigned short*)carve(NW2 * 2);
    unsigned short* Wt3 = (unsigned short*)carve(NW3 * 2);
    float* psum = (float*)carve(N_GRAPHS * F_OUTT * 4);
    int* pcnt = (int*)carve(N_GRAPHS * 4);

    hipMemsetAsync(cnt, 0, N_NODES * 4, stream);
    hipMemsetAsync(fill, 0, N_NODES * 4, stream);
    hipMemsetAsync(psum, 0, N_GRAPHS * F_OUTT * 4, stream);
    hipMemsetAsync(pcnt, 0, N_GRAPHS * 4, stream);

    k_deg<<<(N_EDGES + 255) / 256, 256, 0, stream>>>(row, cnt);
    int nb = (N_NODES + 511) / 512;  // 98
    k_scan1<<<nb, 256, 0, stream>>>(cnt, rp, part, dis);
    k_scan2<<<1, 128, 0, stream>>>(part, nb);
    k_scan3<<<nb, 256, 0, stream>>>(rp, part);
    k_scatter<<<(N_EDGES + 255) / 256, 256, 0, stream>>>(row, col, dis, rp, fill, cw);

    {
        int tot = NX + NW1 + NW2 + NW3;
        k_convAll<<<(tot + 255) / 256, 256, 0, stream>>>(x, W1, W2, W3, xb, Wt1, Wt2,
                                                         Wt3);
    }

    const int spmvGrid = (N_NODES + 3) / 4;

    // Layer 1: in=xb (128) -> out=bufA (192)
    k_spmv<128><<<spmvGrid, 256, 0, stream>>>(rp, cw, xb, xb, 1.f, 0.f, bufB);
    k_spmv<128><<<spmvGrid, 256, 0, stream>>>(rp, cw, bufB, xb, 2.f, -1.f, bufC);
    {
        dim3 g((N_NODES + 127) / 128, 192 / 64);
        k_gemm3<<<g, 256, 0, stream>>>(xb, bufB, bufC, Wt1, b1, bufA, 128, 192);
    }
    // Layer 2: in=bufA (192) -> out=bufD (192)
    k_spmv<192><<<spmvGrid, 256, 0, stream>>>(rp, cw, bufA, bufA, 1.f, 0.f, bufB);
    k_spmv<192><<<spmvGrid, 256, 0, stream>>>(rp, cw, bufB, bufA, 2.f, -1.f, bufC);
    {
        dim3 g((N_NODES + 127) / 128, 192 / 64);
        k_gemm3<<<g, 256, 0, stream>>>(bufA, bufB, bufC, Wt2, b2, bufD, 192, 192);
    }
    // Layer 3: in=bufD (192) -> out=bufA (128)
    k_spmv<192><<<spmvGrid, 256, 0, stream>>>(rp, cw, bufD, bufD, 1.f, 0.f, bufB);
    k_spmv<192><<<spmvGrid, 256, 0, stream>>>(rp, cw, bufB, bufD, 2.f, -1.f, bufC);
    {
        dim3 g((N_NODES + 127) / 128, 128 / 64);
        k_gemm3<<<g, 256, 0, stream>>>(bufD, bufB, bufC, Wt3, b3, bufA, 192, 128);
    }

    k_pool_partial<<<(N_NODES + POOL_CHUNK - 1) / POOL_CHUNK, F_OUTT, 0, stream>>>(
        bufA, batch, psum, pcnt);
    k_head<<<N_GRAPHS, 64, 0, stream>>>(psum, pcnt, fcw, fcb, out);
}

// Round 5
// 537.920 us; speedup vs baseline: 2.5793x; 1.0648x over previous
//
#include <hip/hip_runtime.h>
#include <math.h>

#define N_NODES 50000
#define N_EDGES 800000
#define N_GRAPHS 64
#define F_INN 128
#define F_HID 192
#define F_OUTT 128
#define N_CLS 10
#define POOL_CHUNK 128

typedef short short8 __attribute__((ext_vector_type(8)));
typedef float f32x4 __attribute__((ext_vector_type(4)));

static __device__ inline unsigned short f2bf(float f) {
    unsigned int u = __float_as_uint(f);
    unsigned int r = (u + 0x7FFFu + ((u >> 16) & 1u)) >> 16;  // RNE
    return (unsigned short)r;
}
static __device__ inline float bf2f(unsigned short h) {
    return __uint_as_float(((unsigned int)h) << 16);
}

// ---------------- CSR build ----------------
__global__ void k_deg(const int* __restrict__ row, int* __restrict__ cnt) {
    int e = blockIdx.x * 256 + threadIdx.x;
    if (e < N_EDGES) atomicAdd(&cnt[row[e]], 1);
}

// scan phase 1 + fused dis = rsqrt(deg)
__global__ void k_scan1(const int* __restrict__ cnt, int* __restrict__ rp,
                        int* __restrict__ part, float* __restrict__ dis) {
    __shared__ int s[256];
    int base = blockIdx.x * 512;
    int i0 = base + 2 * threadIdx.x;
    int v0 = (i0 < N_NODES) ? cnt[i0] : 0;
    int v1 = (i0 + 1 < N_NODES) ? cnt[i0 + 1] : 0;
    if (i0 < N_NODES) dis[i0] = v0 > 0 ? rsqrtf((float)v0) : 0.f;
    if (i0 + 1 < N_NODES) dis[i0 + 1] = v1 > 0 ? rsqrtf((float)v1) : 0.f;
    int tsum = v0 + v1;
    s[threadIdx.x] = tsum;
    __syncthreads();
    for (int off = 1; off < 256; off <<= 1) {
        int val = (threadIdx.x >= off) ? s[threadIdx.x - off] : 0;
        __syncthreads();
        s[threadIdx.x] += val;
        __syncthreads();
    }
    int excl = s[threadIdx.x] - tsum;
    if (i0 < N_NODES) rp[i0] = excl;
    if (i0 + 1 < N_NODES) rp[i0 + 1] = excl + v0;
    if (threadIdx.x == 255) part[blockIdx.x] = s[255];
}

__global__ void k_scan2(int* __restrict__ part, int nb) {
    __shared__ int s[128];
    int t = threadIdx.x;
    int v = (t < nb) ? part[t] : 0;
    s[t] = v;
    __syncthreads();
    for (int off = 1; off < 128; off <<= 1) {
        int val = (t >= off) ? s[t - off] : 0;
        __syncthreads();
        s[t] += val;
        __syncthreads();
    }
    if (t < nb) part[t] = s[t] - v;  // exclusive
}

__global__ void k_scan3(int* __restrict__ rp, const int* __restrict__ part) {
    int add = part[blockIdx.x];
    int i0 = blockIdx.x * 512 + 2 * threadIdx.x;
    if (i0 < N_NODES) rp[i0] += add;
    if (i0 + 1 < N_NODES) rp[i0 + 1] += add;
    if (blockIdx.x == 0 && threadIdx.x == 0) rp[N_NODES] = N_EDGES;
}

// packed CSR payload: (col, weight-bits)
__global__ void k_scatter(const int* __restrict__ row, const int* __restrict__ col,
                          const float* __restrict__ dis, const int* __restrict__ rp,
                          int* __restrict__ fill, int2* __restrict__ cw) {
    int e = blockIdx.x * 256 + threadIdx.x;
    if (e < N_EDGES) {
        int r = row[e], c = col[e];
        int pos = rp[r] + atomicAdd(&fill[r], 1);
        int2 v;
        v.x = c;
        v.y = __float_as_int(-dis[r] * dis[c]);
        cw[pos] = v;
    }
}

// ---------------- fused fp32->bf16 conversions (x + 3 transposed W) --------
#define NX (N_NODES * F_INN)
#define NW1 (3 * 128 * 192)
#define NW2 (3 * 192 * 192)
#define NW3 (3 * 192 * 128)
__global__ void k_convAll(const float* __restrict__ x, const float* __restrict__ W1,
                          const float* __restrict__ W2, const float* __restrict__ W3,
                          unsigned short* __restrict__ xb,
                          unsigned short* __restrict__ Wt1,
                          unsigned short* __restrict__ Wt2,
                          unsigned short* __restrict__ Wt3) {
    int idx = blockIdx.x * 256 + threadIdx.x;
    if (idx < NX) {
        xb[idx] = f2bf(x[idx]);
        return;
    }
    idx -= NX;
    if (idx < NW1) {  // W1[j][k][n] -> Wt1[j][n][k], Fin=128, Fout=192
        int per = 128 * 192;
        int j = idx / per, r = idx - j * per;
        int k = r / 192, n = r - k * 192;
        Wt1[j * per + n * 128 + k] = f2bf(W1[idx]);
        return;
    }
    idx -= NW1;
    if (idx < NW2) {  // Fin=192, Fout=192
        int per = 192 * 192;
        int j = idx / per, r = idx - j * per;
        int k = r / 192, n = r - k * 192;
        Wt2[j * per + n * 192 + k] = f2bf(W2[idx]);
        return;
    }
    idx -= NW2;
    if (idx < NW3) {  // Fin=192, Fout=128
        int per = 192 * 128;
        int j = idx / per, r = idx - j * per;
        int k = r / 128, n = r - k * 128;
        Wt3[j * per + n * 192 + k] = f2bf(W3[idx]);
    }
}

// ---------------- SpMV (bf16 in/out, fp32 accum) ----------------
// y = alpha*(L_hat@h) + beta*z. One wave per row. Lane l owns feats
// {2l, 2l+1} (packed uint gather) + feat 128+l (ushort) for F=192.
// Edge metadata (rp bounds, col, w) is wave-uniform -> readfirstlane
// scalarizes address math + weight operand; edge loop unrolled x8 so
// 8 (16 for F=192) gather latency chains overlap.
template <int F>
__global__ void k_spmv(const int* __restrict__ rp, const int2* __restrict__ cw,
                       const unsigned short* __restrict__ h,
                       const unsigned short* __restrict__ z, float alpha, float beta,
                       unsigned short* __restrict__ y) {
    constexpr bool EX = (F > 128);
    constexpr int FU = F / 2;  // uints per row
    int wave = threadIdx.x >> 6;
    int lane = threadIdx.x & 63;
    int r = blockIdx.x * 4 + wave;
    if (r >= N_NODES) return;
    int e0 = __builtin_amdgcn_readfirstlane(rp[r]);
    int e1 = __builtin_amdgcn_readfirstlane(rp[r + 1]);
    const unsigned int* hu = (const unsigned int*)h;
    float a0 = 0.f, a1 = 0.f, a2 = 0.f;
    int e = e0;
    for (; e + 8 <= e1; e += 8) {
        int colv[8];
        float wv[8];
#pragma unroll
        for (int u = 0; u < 8; u++) {
            int2 p = cw[e + u];
            colv[u] = __builtin_amdgcn_readfirstlane(p.x);
            wv[u] = __uint_as_float(__builtin_amdgcn_readfirstlane(p.y));
        }
        unsigned int g[8];
        unsigned short s[8];
#pragma unroll
        for (int u = 0; u < 8; u++) {
            g[u] = hu[colv[u] * FU + lane];
            if constexpr (EX) s[u] = h[colv[u] * F + 128 + lane];
        }
#pragma unroll
        for (int u = 0; u < 8; u++) {
            a0 += wv[u] * bf2f((unsigned short)g[u]);
            a1 += wv[u] * bf2f((unsigned short)(g[u] >> 16));
            if constexpr (EX) a2 += wv[u] * bf2f(s[u]);
        }
    }
    for (; e + 4 <= e1; e += 4) {
        int colv[4];
        float wv[4];
#pragma unroll
        for (int u = 0; u < 4; u++) {
            int2 p = cw[e + u];
            colv[u] = __builtin_amdgcn_readfirstlane(p.x);
            wv[u] = __uint_as_float(__builtin_amdgcn_readfirstlane(p.y));
        }
        unsigned int g[4];
        unsigned short s[4];
#pragma unroll
        for (int u = 0; u < 4; u++) {
            g[u] = hu[colv[u] * FU + lane];
            if constexpr (EX) s[u] = h[colv[u] * F + 128 + lane];
        }
#pragma unroll
        for (int u = 0; u < 4; u++) {
            a0 += wv[u] * bf2f((unsigned short)g[u]);
            a1 += wv[u] * bf2f((unsigned short)(g[u] >> 16));
            if constexpr (EX) a2 += wv[u] * bf2f(s[u]);
        }
    }
    for (; e < e1; e++) {
        int2 p = cw[e];
        int c = __builtin_amdgcn_readfirstlane(p.x);
        float w = __uint_as_float(__builtin_amdgcn_readfirstlane(p.y));
        unsigned int g = hu[c * FU + lane];
        a0 += w * bf2f((unsigned short)g);
        a1 += w * bf2f((unsigned short)(g >> 16));
        if constexpr (EX) a2 += w * bf2f(h[c * F + 128 + lane]);
    }
    float v0 = alpha * a0, v1 = alpha * a1, v2 = alpha * a2;
    if (beta != 0.f) {
        unsigned int zg = ((const unsigned int*)z)[r * FU + lane];
        v0 += beta * bf2f((unsigned short)zg);
        v1 += beta * bf2f((unsigned short)(zg >> 16));
        if constexpr (EX) v2 += beta * bf2f(z[r * F + 128 + lane]);
    }
    ((unsigned int*)y)[r * FU + lane] =
        (unsigned int)f2bf(v0) | ((unsigned int)f2bf(v1) << 16);
    if constexpr (EX) y[r * F + 128 + lane] = f2bf(v2);
}

// ---------------- fused 3-matrix bf16 MFMA GEMM ----------------
// C = A0@W[0]+A1@W[1]+A2@W[2]+bias, A row-major [M][Fin] bf16,
// Wt pre-transposed [3][Fout][Fin] bf16, C bf16 [M][Fout].
// Block: 256 thr = 4 waves; tile M=128 x N=64; wave = 32 rows x 64 cols
// = 2x4 grid of 16x16x32 MFMAs. LDS stride 40 shorts breaks pow-2 conflicts.
__global__ __launch_bounds__(256) void k_gemm3(
    const unsigned short* __restrict__ A0, const unsigned short* __restrict__ A1,
    const unsigned short* __restrict__ A2, const unsigned short* __restrict__ Wt,
    const float* __restrict__ bias, unsigned short* __restrict__ C, int Fin,
    int Fout) {
    __shared__ unsigned short As[128 * 40];
    __shared__ unsigned short Bs[64 * 40];
    int t = threadIdx.x;
    int w = t >> 6;
    int lane = t & 63;
    int ml = lane & 15;
    int quad = lane >> 4;
    int mBase = blockIdx.x * 128;
    int nBase = blockIdx.y * 64;
    int per = Fin * Fout;

    f32x4 acc[2][4];
#pragma unroll
    for (int i = 0; i < 2; i++)
#pragma unroll
        for (int jn = 0; jn < 4; jn++) acc[i][jn] = (f32x4){0.f, 0.f, 0.f, 0.f};

    int srow = t >> 2;   // 0..63
    int schunk = t & 3;  // 16B chunk within 32-k slab
    int nChunks = (3 * Fin) >> 5;

    for (int ch = 0; ch < nChunks; ch++) {
        int kg = ch << 5;
        int j = kg / Fin;
        int kk = kg - j * Fin;
        const unsigned short* Aj = (j == 0) ? A0 : (j == 1) ? A1 : A2;
        if (ch > 0) __syncthreads();
#pragma unroll
        for (int pass = 0; pass < 2; pass++) {
            int row = srow + pass * 64;
            int gm = mBase + row;
            uint4 v = {0u, 0u, 0u, 0u};
            if (gm < N_NODES)
                v = *(const uint4*)(Aj + (size_t)gm * Fin + kk + schunk * 8);
            *(uint4*)&As[row * 40 + schunk * 8] = v;
        }
        {
            const unsigned short* src =
                Wt + (size_t)j * per + (size_t)(nBase + srow) * Fin + kk + schunk * 8;
            *(uint4*)&Bs[srow * 40 + schunk * 8] = *(const uint4*)src;
        }
        __syncthreads();

        short8 afr[2], bfr[4];
#pragma unroll
        for (int i = 0; i < 2; i++)
            afr[i] = *(const short8*)&As[(w * 32 + i * 16 + ml) * 40 + quad * 8];
#pragma unroll
        for (int jn = 0; jn < 4; jn++)
            bfr[jn] = *(const short8*)&Bs[(jn * 16 + ml) * 40 + quad * 8];
#pragma unroll
        for (int i = 0; i < 2; i++)
#pragma unroll
            for (int jn = 0; jn < 4; jn++)
                acc[i][jn] = __builtin_amdgcn_mfma_f32_16x16x32_bf16(
                    afr[i], bfr[jn], acc[i][jn], 0, 0, 0);
    }

    float biasv[4];
#pragma unroll
    for (int jn = 0; jn < 4; jn++) biasv[jn] = bias[nBase + jn * 16 + ml];

#pragma unroll
    for (int i = 0; i < 2; i++) {
#pragma unroll
        for (int r = 0; r < 4; r++) {
            int m = mBase + w * 32 + i * 16 + quad * 4 + r;
            if (m < N_NODES) {
                unsigned short* cp = C + (size_t)m * Fout + nBase + ml;
#pragma unroll
                for (int jn = 0; jn < 4; jn++)
                    cp[jn * 16] = f2bf(acc[i][jn][r] + biasv[jn]);
            }
        }
    }
}

// ---------------- pooling: chunked partial sums + atomics ----------------
__global__ void k_pool_partial(const unsigned short* __restrict__ h,
                               const int* __restrict__ batch,
                               float* __restrict__ psum, int* __restrict__ pcnt) {
    int f = threadIdx.x;  // 128
    int n0 = blockIdx.x * POOL_CHUNK;
    int n1 = n0 + POOL_CHUNK;
    if (n1 > N_NODES) n1 = N_NODES;
    if (n0 >= N_NODES) return;
    int curg = batch[n0];
    float acc = 0.f;
    int run = 0;
    for (int n = n0; n < n1; n++) {
        int g = batch[n];
        if (g != curg) {
            atomicAdd(&psum[curg * F_OUTT + f], acc);
            if (f == 0) atomicAdd(&pcnt[curg], run);
            acc = 0.f;
            run = 0;
            curg = g;
        }
        acc += bf2f(h[(size_t)n * F_OUTT + f]);
        run++;
    }
    atomicAdd(&psum[curg * F_OUTT + f], acc);
    if (f == 0) atomicAdd(&pcnt[curg], run);
}

__global__ void k_head(const float* __restrict__ psum, const int* __restrict__ pcnt,
                       const float* __restrict__ fcw, const float* __restrict__ fcb,
                       float* __restrict__ out) {
    int g = blockIdx.x;
    int c = threadIdx.x;  // 64 threads, lanes >= N_CLS idle
    __shared__ float sl[N_CLS];
    float inv = 1.f / fmaxf((float)pcnt[g], 1.f);
    float l = 0.f;
    if (c < N_CLS) {
        l = fcb[c];
        for (int k = 0; k < F_OUTT; k++)
            l += psum[g * F_OUTT + k] * inv * fcw[k * N_CLS + c];
        sl[c] = l;
    }
    __syncthreads();
    if (c < N_CLS) {
        float m = -1e30f;
        for (int i = 0; i < N_CLS; i++) m = fmaxf(m, sl[i]);
        float s = 0.f;
        for (int i = 0; i < N_CLS; i++) s += expf(sl[i] - m);
        out[g * N_CLS + c] = l - m - logf(s);
    }
}

extern "C" void kernel_launch(void* const* d_in, const int* in_sizes, int n_in,
                              void* d_out, int out_size, void* d_ws, size_t ws_size,
                              hipStream_t stream) {
    const float* x = (const float*)d_in[0];
    const int* ei = (const int*)d_in[1];
    const int* batch = (const int*)d_in[2];
    const float* W1 = (const float*)d_in[3];
    const float* b1 = (const float*)d_in[4];
    const float* W2 = (const float*)d_in[5];
    const float* b2 = (const float*)d_in[6];
    const float* W3 = (const float*)d_in[7];
    const float* b3 = (const float*)d_in[8];
    const float* fcw = (const float*)d_in[9];
    const float* fcb = (const float*)d_in[10];
    float* out = (float*)d_out;
    const int* row = ei;
    const int* col = ei + N_EDGES;

    char* p = (char*)d_ws;
    auto carve = [&](size_t bytes) {
        char* q = p;
        p += (bytes + 255) & ~(size_t)255;
        return q;
    };
    int* cnt = (int*)carve(N_NODES * 4);
    int* fill = (int*)carve(N_NODES * 4);
    float* dis = (float*)carve(N_NODES * 4);
    int* rp = (int*)carve((N_NODES + 1) * 4);
    int* part = (int*)carve(128 * 4);
    int2* cw = (int2*)carve((size_t)N_EDGES * 8);
    unsigned short* xb = (unsigned short*)carve((size_t)N_NODES * F_INN * 2);
    size_t hbytes = (size_t)N_NODES * 192 * 2;
    unsigned short* bufA = (unsigned short*)carve(hbytes);
    unsigned short* bufB = (unsigned short*)carve(hbytes);
    unsigned short* bufC = (unsigned short*)carve(hbytes);
    unsigned short* bufD = (unsigned short*)carve(hbytes);
    unsigned short* Wt1 = (unsigned short*)carve(NW1 * 2);
    unsigned short* Wt2 = (unsigned short*)carve(NW2 * 2);
    unsigned short* Wt3 = (unsigned short*)carve(NW3 * 2);
    float* psum = (float*)carve(N_GRAPHS * F_OUTT * 4);
    int* pcnt = (int*)carve(N_GRAPHS * 4);

    hipMemsetAsync(cnt, 0, N_NODES * 4, stream);
    hipMemsetAsync(fill, 0, N_NODES * 4, stream);
    hipMemsetAsync(psum, 0, N_GRAPHS * F_OUTT * 4, stream);
    hipMemsetAsync(pcnt, 0, N_GRAPHS * 4, stream);

    k_deg<<<(N_EDGES + 255) / 256, 256, 0, stream>>>(row, cnt);
    int nb = (N_NODES + 511) / 512;  // 98
    k_scan1<<<nb, 256, 0, stream>>>(cnt, rp, part, dis);
    k_scan2<<<1, 128, 0, stream>>>(part, nb);
    k_scan3<<<nb, 256, 0, stream>>>(rp, part);
    k_scatter<<<(N_EDGES + 255) / 256, 256, 0, stream>>>(row, col, dis, rp, fill, cw);

    {
        int tot = NX + NW1 + NW2 + NW3;
        k_convAll<<<(tot + 255) / 256, 256, 0, stream>>>(x, W1, W2, W3, xb, Wt1, Wt2,
                                                         Wt3);
    }

    const int spmvGrid = (N_NODES + 3) / 4;

    // Layer 1: in=xb (128) -> out=bufA (192)
    k_spmv<128><<<spmvGrid, 256, 0, stream>>>(rp, cw, xb, xb, 1.f, 0.f, bufB);
    k_spmv<128><<<spmvGrid, 256, 0, stream>>>(rp, cw, bufB, xb, 2.f, -1.f, bufC);
    {
        dim3 g((N_NODES + 127) / 128, 192 / 64);
        k_gemm3<<<g, 256, 0, stream>>>(xb, bufB, bufC, Wt1, b1, bufA, 128, 192);
    }
    // Layer 2: in=bufA (192) -> out=bufD (192)
    k_spmv<192><<<spmvGrid, 256, 0, stream>>>(rp, cw, bufA, bufA, 1.f, 0.f, bufB);
    k_spmv<192><<<spmvGrid, 256, 0, stream>>>(rp, cw, bufB, bufA, 2.f, -1.f, bufC);
    {
        dim3 g((N_NODES + 127) / 128, 192 / 64);
        k_gemm3<<<g, 256, 0, stream>>>(bufA, bufB, bufC, Wt2, b2, bufD, 192, 192);
    }
    // Layer 3: in=bufD (192) -> out=bufA (128)
    k_spmv<192><<<spmvGrid, 256, 0, stream>>>(rp, cw, bufD, bufD, 1.f, 0.f, bufB);
    k_spmv<192><<<spmvGrid, 256, 0, stream>>>(rp, cw, bufB, bufD, 2.f, -1.f, bufC);
    {
        dim3 g((N_NODES + 127) / 128, 128 / 64);
        k_gemm3<<<g, 256, 0, stream>>>(bufD, bufB, bufC, Wt3, b3, bufA, 192, 128);
    }

    k_pool_partial<<<(N_NODES + POOL_CHUNK - 1) / POOL_CHUNK, F_OUTT, 0, stream>>>(
        bufA, batch, psum, pcnt);
    k_head<<<N_GRAPHS, 64, 0, stream>>>(psum, pcnt, fcw, fcb, out);
}